// Round 1
// baseline (10147.728 us; speedup 1.0000x reference)
//
#include <hip/hip_runtime.h>
#include <math.h>

#define NLAB 28000
#define NEDGE 224000

// ---------------------------------------------------------------- utils

__device__ __forceinline__ void atomAddF(float* p, float v) {
  unsafeAtomicAdd(p, v);   // gfx950: global_atomic_add_f32
}

struct RecurArgs {
  const float* gx[4];
  const float* wT[4];
  const float* bh[4];
  float* out[4];
  const int* len[4];
  int Tl[4];
  int dir[4];
};

// ---------------------------------------------------------------- embed

__global__ void embed_gather(const int* __restrict__ tok, const float* __restrict__ emb,
                             float* __restrict__ x, int rows) {
  int idx = blockIdx.x * blockDim.x + threadIdx.x;
  if (idx >= rows * 50) return;
  int r = idx / 50, c = idx - r * 50;
  *(float4*)&x[(size_t)r * 200 + c * 4] =
      *(const float4*)&emb[(size_t)tok[r] * 200 + c * 4];
}

// ---------------------------------------------------------------- whh transpose [600,200] -> [200,600]

__global__ void transpose_whh(const float* __restrict__ whh, float* __restrict__ wT) {
  int idx = blockIdx.x * blockDim.x + threadIdx.x;
  if (idx >= 600 * 200) return;
  int g = idx / 200, k = idx - g * 200;
  wT[k * 600 + g] = whh[idx];
}

// ---------------------------------------------------------------- GCN scatter-add (one wave per edge)

__global__ void gcn_gather(const float* __restrict__ feat, const int* __restrict__ src,
                           const int* __restrict__ dst, float* __restrict__ agg) {
  int wave = (int)((blockIdx.x * blockDim.x + threadIdx.x) >> 6);
  int lane = threadIdx.x & 63;
  if (wave >= NEDGE || lane >= 50) return;
  int s = src[wave], d = dst[wave];
  float4 v = *(const float4*)&feat[(size_t)s * 200 + lane * 4];
  float* p = &agg[(size_t)d * 200 + lane * 4];
  atomAddF(p + 0, v.x); atomAddF(p + 1, v.y);
  atomAddF(p + 2, v.z); atomAddF(p + 3, v.w);
}

// ---------------------------------------------------------------- generic C[M,N] = A[M,K] * W[N,K]^T (+bias)(+relu)

template <int RELU, int BIAS>
__global__ __launch_bounds__(256, 2) void gemm_nt(
    const float* __restrict__ A, const float* __restrict__ Wt,
    const float* __restrict__ bias, float* __restrict__ C,
    int M, int N, int K) {
  __shared__ float As[16][68];
  __shared__ float Bs[16][68];
  int tx = threadIdx.x & 15, ty = threadIdx.x >> 4;
  int m0 = blockIdx.y * 64, n0 = blockIdx.x * 64;
  float c[4][4] = {};
  int row = threadIdx.x >> 2;
  int kk = (threadIdx.x & 3) * 4;
  for (int k0 = 0; k0 < K; k0 += 16) {
    int gk = k0 + kk;
    float a0 = 0, a1 = 0, a2 = 0, a3 = 0;
    float b0 = 0, b1 = 0, b2 = 0, b3 = 0;
    int gm = m0 + row;
    if (gm < M) {
      if (gk + 3 < K) {
        float4 v = *(const float4*)&A[(size_t)gm * K + gk];
        a0 = v.x; a1 = v.y; a2 = v.z; a3 = v.w;
      } else {
        if (gk + 0 < K) a0 = A[(size_t)gm * K + gk + 0];
        if (gk + 1 < K) a1 = A[(size_t)gm * K + gk + 1];
        if (gk + 2 < K) a2 = A[(size_t)gm * K + gk + 2];
        if (gk + 3 < K) a3 = A[(size_t)gm * K + gk + 3];
      }
    }
    int gn = n0 + row;
    if (gn < N) {
      if (gk + 3 < K) {
        float4 v = *(const float4*)&Wt[(size_t)gn * K + gk];
        b0 = v.x; b1 = v.y; b2 = v.z; b3 = v.w;
      } else {
        if (gk + 0 < K) b0 = Wt[(size_t)gn * K + gk + 0];
        if (gk + 1 < K) b1 = Wt[(size_t)gn * K + gk + 1];
        if (gk + 2 < K) b2 = Wt[(size_t)gn * K + gk + 2];
        if (gk + 3 < K) b3 = Wt[(size_t)gn * K + gk + 3];
      }
    }
    As[kk + 0][row] = a0; As[kk + 1][row] = a1; As[kk + 2][row] = a2; As[kk + 3][row] = a3;
    Bs[kk + 0][row] = b0; Bs[kk + 1][row] = b1; Bs[kk + 2][row] = b2; Bs[kk + 3][row] = b3;
    __syncthreads();
#pragma unroll
    for (int k = 0; k < 16; k++) {
      float4 a4 = *(const float4*)&As[k][ty * 4];
      float4 b4 = *(const float4*)&Bs[k][tx * 4];
      c[0][0] = fmaf(a4.x, b4.x, c[0][0]); c[0][1] = fmaf(a4.x, b4.y, c[0][1]);
      c[0][2] = fmaf(a4.x, b4.z, c[0][2]); c[0][3] = fmaf(a4.x, b4.w, c[0][3]);
      c[1][0] = fmaf(a4.y, b4.x, c[1][0]); c[1][1] = fmaf(a4.y, b4.y, c[1][1]);
      c[1][2] = fmaf(a4.y, b4.z, c[1][2]); c[1][3] = fmaf(a4.y, b4.w, c[1][3]);
      c[2][0] = fmaf(a4.z, b4.x, c[2][0]); c[2][1] = fmaf(a4.z, b4.y, c[2][1]);
      c[2][2] = fmaf(a4.z, b4.z, c[2][2]); c[2][3] = fmaf(a4.z, b4.w, c[2][3]);
      c[3][0] = fmaf(a4.w, b4.x, c[3][0]); c[3][1] = fmaf(a4.w, b4.y, c[3][1]);
      c[3][2] = fmaf(a4.w, b4.z, c[3][2]); c[3][3] = fmaf(a4.w, b4.w, c[3][3]);
    }
    __syncthreads();
  }
#pragma unroll
  for (int i = 0; i < 4; i++) {
    int gm = m0 + ty * 4 + i;
    if (gm >= M) continue;
#pragma unroll
    for (int j = 0; j < 4; j++) {
      int gn = n0 + tx * 4 + j;
      if (gn >= N) continue;
      float v = c[i][j];
      if (BIAS) v += bias[gn];
      if (RELU) v = fmaxf(v, 0.f);
      C[(size_t)gm * N + gn] = v;
    }
  }
}

// ---------------------------------------------------------------- GRU recurrence: one block per (branch,dir) chain

__global__ __launch_bounds__(640, 1) void gru_recur(RecurArgs a) {
  int blk = blockIdx.x;
  const float* __restrict__ gx = a.gx[blk];
  const float* __restrict__ wT = a.wT[blk];
  const float* __restrict__ bh = a.bh[blk];
  float* __restrict__ outp = a.out[blk];
  const int* lenp = a.len[blk];
  int TT = a.Tl[blk];
  int bwd = a.dir[blk];
  int dirOff = bwd ? 200 : 0;

  __shared__ float h[200][4];
  __shared__ float gh[600][4];
  __shared__ float bhs[600];
  __shared__ int lens[4];
  int tid = threadIdx.x;
  for (int i = tid; i < 800; i += 640) ((float*)h)[i] = 0.f;
  for (int i = tid; i < 600; i += 640) bhs[i] = bh[i];
  if (tid < 4) lens[tid] = lenp[tid];
  __syncthreads();
  int maxlen = max(max(lens[0], lens[1]), max(lens[2], lens[3]));

  for (int s = 0; s < maxlen; s++) {
    // phase A: gh[g][b] = sum_k whh[g,k] * h[k][b]  (+bhh)
    if (tid < 600) {
      float a0 = 0, a1 = 0, a2 = 0, a3 = 0;
      const float* wc = wT + tid;
#pragma unroll 8
      for (int k = 0; k < 200; k++) {
        float w = wc[k * 600];
        float4 hv = *(const float4*)&h[k][0];
        a0 = fmaf(w, hv.x, a0); a1 = fmaf(w, hv.y, a1);
        a2 = fmaf(w, hv.z, a2); a3 = fmaf(w, hv.w, a3);
      }
      float bb = bhs[tid];
      gh[tid][0] = a0 + bb; gh[tid][1] = a1 + bb;
      gh[tid][2] = a2 + bb; gh[tid][3] = a3 + bb;
    }
    __syncthreads();
    // phase B: gates + h update + output write
    for (int it = tid; it < 800; it += 640) {
      int i = it >> 2, b = it & 3;
      int Lb = lens[b];
      if (s < Lb) {
        int ta = bwd ? (Lb - 1 - s) : s;
        const float* gxr = gx + (size_t)(b * TT + ta) * 600;
        float r = 1.f / (1.f + expf(-(gxr[i] + gh[i][b])));
        float z = 1.f / (1.f + expf(-(gxr[200 + i] + gh[200 + i][b])));
        float n = tanhf(gxr[400 + i] + r * gh[400 + i][b]);
        float hn = (1.f - z) * n + z * h[i][b];
        h[i][b] = hn;
        outp[(size_t)(b * TT + ta) * 400 + dirOff + i] = hn;
      }
    }
    __syncthreads();
  }
}

// ---------------------------------------------------------------- fused cross-attention + fc1 + fc2

#define XTS 604
__global__ __launch_bounds__(512, 1) void attention_fused(
    const float* __restrict__ x_ti, const float* __restrict__ xf_ti,
    const float* __restrict__ x_ab, const float* __restrict__ xf_ab,
    const float* __restrict__ lab, const float* __restrict__ gnf,
    const float* __restrict__ fc1b, const float* __restrict__ fc2w,
    const float* __restrict__ fc2b, float* __restrict__ outp) {
  __shared__ float lf[32][400];   // label_feature tile [lab | gnf]
  __shared__ float xt[32][XTS];   // per-t row: [x(400) | xf1(200)]
  __shared__ float S2[2][32][33]; // K-half partial logits, then P

  int tid = threadIdx.x;
  int b = blockIdx.y;
  int n0 = blockIdx.x * 32;

  for (int u = tid; u < 32 * 100; u += 512) {
    int n = u / 100, c4 = (u - n * 100) * 4;
    float4 v = (c4 < 200) ? *(const float4*)&lab[(size_t)(n0 + n) * 200 + c4]
                          : *(const float4*)&gnf[(size_t)(n0 + n) * 200 + (c4 - 200)];
    *(float4*)&lf[n][c4] = v;
  }

  int apair = tid >> 5;        // 0..15 : n-pair
  int tb = tid & 15;           // t base
  int hh = (tid >> 4) & 1;     // K half
  int n_pv = tid >> 4;         // 0..31 : n for softmax/PV
  int dg = tid & 15;           // d group
  int d0 = dg < 8 ? dg * 13 : 104 + (dg - 8) * 12;
  int nd = dg < 8 ? 13 : 12;

  float y1[13];
#pragma unroll
  for (int j = 0; j < 13; j++) y1[j] = 0.f;

  for (int br = 0; br < 2; br++) {
    const float* xp = br ? x_ab : x_ti;
    const float* xf = br ? xf_ab : xf_ti;
    int T = br ? 384 : 64;
    float m_run = -INFINITY, l_run = 0.f;
    float acc[13];
#pragma unroll
    for (int j = 0; j < 13; j++) acc[j] = 0.f;

    for (int t0 = 0; t0 < T; t0 += 32) {
      __syncthreads();  // protect xt/S2 from previous tile readers
      for (int u = tid; u < 32 * 150; u += 512) {
        int row = u / 150, c4 = (u - row * 150) * 4;
        int gt = t0 + row;
        float4 v = (c4 < 400)
            ? *(const float4*)&xp[((size_t)(b * T + gt)) * 400 + c4]
            : *(const float4*)&xf[((size_t)(b * T + gt)) * 200 + (c4 - 400)];
        *(float4*)&xt[row][c4] = v;
      }
      __syncthreads();

      // logits: S[n][t] = lf[n] . x[t]  (each thread: 2n x 2t over one K-half)
      float s00 = 0, s01 = 0, s10 = 0, s11 = 0;
      int na0 = apair * 2, na1 = na0 + 1;
#pragma unroll 4
      for (int k4 = 0; k4 < 50; k4++) {
        int kc = hh * 200 + k4 * 4;
        float4 l0 = *(const float4*)&lf[na0][kc];
        float4 l1 = *(const float4*)&lf[na1][kc];
        float4 x0 = *(const float4*)&xt[tb][kc];
        float4 x1 = *(const float4*)&xt[tb + 16][kc];
        s00 = fmaf(l0.x, x0.x, s00); s00 = fmaf(l0.y, x0.y, s00);
        s00 = fmaf(l0.z, x0.z, s00); s00 = fmaf(l0.w, x0.w, s00);
        s01 = fmaf(l0.x, x1.x, s01); s01 = fmaf(l0.y, x1.y, s01);
        s01 = fmaf(l0.z, x1.z, s01); s01 = fmaf(l0.w, x1.w, s01);
        s10 = fmaf(l1.x, x0.x, s10); s10 = fmaf(l1.y, x0.y, s10);
        s10 = fmaf(l1.z, x0.z, s10); s10 = fmaf(l1.w, x0.w, s10);
        s11 = fmaf(l1.x, x1.x, s11); s11 = fmaf(l1.y, x1.y, s11);
        s11 = fmaf(l1.z, x1.z, s11); s11 = fmaf(l1.w, x1.w, s11);
      }
      S2[hh][na0][tb] = s00; S2[hh][na0][tb + 16] = s01;
      S2[hh][na1][tb] = s10; S2[hh][na1][tb + 16] = s11;
      __syncthreads();

      // online softmax (per n over this 32-t tile)
      float sA = S2[0][n_pv][dg] + S2[1][n_pv][dg];
      float sB = S2[0][n_pv][dg + 16] + S2[1][n_pv][dg + 16];
      float tmax = fmaxf(sA, sB);
#pragma unroll
      for (int o = 8; o >= 1; o >>= 1) tmax = fmaxf(tmax, __shfl_xor(tmax, o));
      float mn = fmaxf(m_run, tmax);
      float cr = expf(m_run - mn);  // first tile: exp(-inf)=0
      float pA = expf(sA - mn), pB = expf(sB - mn);
      float ts = pA + pB;
#pragma unroll
      for (int o = 8; o >= 1; o >>= 1) ts += __shfl_xor(ts, o);
      l_run = l_run * cr + ts;
      m_run = mn;
      S2[0][n_pv][dg] = pA;
      S2[0][n_pv][dg + 16] = pB;
      __syncthreads();

      // PV: acc[d] = acc[d]*cr + sum_t P[t] * xf1[t][d]
#pragma unroll
      for (int j = 0; j < 13; j++) acc[j] *= cr;
      for (int t = 0; t < 32; t++) {
        float p = S2[0][n_pv][t];
#pragma unroll
        for (int j = 0; j < 13; j++)
          if (j < nd) acc[j] = fmaf(p, xt[t][400 + d0 + j], acc[j]);
      }
    }
    float inv = 1.f / l_run;
#pragma unroll
    for (int j = 0; j < 13; j++) y1[j] += acc[j] * inv;
  }

  // epilogue: leaky(fc1) then fc2 reduce over the 16-lane n-group
  float part = 0.f;
#pragma unroll
  for (int j = 0; j < 13; j++) {
    if (j < nd) {
      float v = y1[j] + fc1b[d0 + j];
      v = v >= 0.f ? v : 0.2f * v;
      part = fmaf(v, fc2w[d0 + j], part);
    }
  }
#pragma unroll
  for (int o = 8; o >= 1; o >>= 1) part += __shfl_xor(part, o);
  if (dg == 0) {
    float v = part + fc2b[0];
    v = v >= 0.f ? v : 0.2f * v;
    outp[(size_t)b * NLAB + n0 + n_pv] = v;
  }
}

// ---------------------------------------------------------------- launch

extern "C" void kernel_launch(void* const* d_in, const int* in_sizes, int n_in,
                              void* d_out, int out_size, void* d_ws, size_t ws_size,
                              hipStream_t stream) {
  (void)in_sizes; (void)n_in; (void)out_size; (void)ws_size;
  const int* tok_ab = (const int*)d_in[0];
  const int* tok_ti = (const int*)d_in[1];
  const int* len_ab = (const int*)d_in[2];
  const int* len_ti = (const int*)d_in[3];
  const int* esrc = (const int*)d_in[4];
  const int* edst = (const int*)d_in[5];
  const float* gnf = (const float*)d_in[6];
  const float* emb = (const float*)d_in[7];
  const float* wih0f = (const float*)d_in[8],  *whh0f = (const float*)d_in[9];
  const float* bih0f = (const float*)d_in[10], *bhh0f = (const float*)d_in[11];
  const float* wih0b = (const float*)d_in[12], *whh0b = (const float*)d_in[13];
  const float* bih0b = (const float*)d_in[14], *bhh0b = (const float*)d_in[15];
  const float* wih1f = (const float*)d_in[16], *whh1f = (const float*)d_in[17];
  const float* bih1f = (const float*)d_in[18], *bhh1f = (const float*)d_in[19];
  const float* wih1b = (const float*)d_in[20], *whh1b = (const float*)d_in[21];
  const float* bih1b = (const float*)d_in[22], *bhh1b = (const float*)d_in[23];
  const float* gw1 = (const float*)d_in[24], *gb1 = (const float*)d_in[25];
  const float* gw2 = (const float*)d_in[26], *gb2 = (const float*)d_in[27];
  const float* fc1w = (const float*)d_in[28], *fc1b = (const float*)d_in[29];
  const float* fc2w = (const float*)d_in[30], *fc2b = (const float*)d_in[31];

  float* W = (float*)d_ws;
  float* agg  = W;             // 5,600,000 f  (overlaid by GRU scratch afterwards)
  float* hbuf = W + 5600000;   // 5,600,000 f
  float* lab  = W + 11200000;  // 5,600,000 f
  // overlay region (inside agg, used only after GCN is done):
  float* whhT   = W;            // 480,000
  float* x0ab   = W + 480000;   // 307,200
  float* x0ti   = W + 787200;   // 51,200
  float* gxfab  = W + 838400;   // 921,600
  float* gxbab  = W + 1760000;  // 921,600
  float* gxfti  = W + 2681600;  // 153,600
  float* gxbti  = W + 2835200;  // 153,600
  float* out0ab = W + 2988800;  // 614,400
  float* out0ti = W + 3603200;  // 102,400
  float* out1ab = W + 3705600;  // 614,400
  float* out1ti = W + 4320000;  // 102,400
  float* xf1ab  = W + 4422400;  // 307,200
  float* xf1ti  = W + 4729600;  // 51,200

  int gatherBlocks = NEDGE / 4;  // one wave per edge, 4 waves/block
  dim3 gGcn(4, 438);             // N=200 -> 4 tiles, M=28000 -> 438 tiles

  // ---- GCN ----
  hipMemsetAsync(agg, 0, 5600000 * sizeof(float), stream);
  gcn_gather<<<gatherBlocks, 256, 0, stream>>>(gnf, esrc, edst, agg);
  gemm_nt<1, 1><<<gGcn, 256, 0, stream>>>(agg, gw1, gb1, hbuf, NLAB, 200, 200);
  hipMemsetAsync(agg, 0, 5600000 * sizeof(float), stream);
  gcn_gather<<<gatherBlocks, 256, 0, stream>>>(hbuf, esrc, edst, agg);
  gemm_nt<0, 1><<<gGcn, 256, 0, stream>>>(agg, gw2, gb2, lab, NLAB, 200, 200);

  // ---- GRU prep (now safe to overlay agg) ----
  transpose_whh<<<(120000 + 255) / 256, 256, 0, stream>>>(whh0f, whhT + 0);
  transpose_whh<<<(120000 + 255) / 256, 256, 0, stream>>>(whh0b, whhT + 120000);
  transpose_whh<<<(120000 + 255) / 256, 256, 0, stream>>>(whh1f, whhT + 240000);
  transpose_whh<<<(120000 + 255) / 256, 256, 0, stream>>>(whh1b, whhT + 360000);
  embed_gather<<<(1536 * 50 + 255) / 256, 256, 0, stream>>>(tok_ab, emb, x0ab, 1536);
  embed_gather<<<(256 * 50 + 255) / 256, 256, 0, stream>>>(tok_ti, emb, x0ti, 256);
  // zero out0ab..out1ti (contiguous) for padded-position zeros
  hipMemsetAsync(out0ab, 0, (size_t)1433600 * sizeof(float), stream);

  dim3 gGxAb(10, 24), gGxTi(10, 4);
  gemm_nt<0, 1><<<gGxAb, 256, 0, stream>>>(x0ab, wih0f, bih0f, gxfab, 1536, 600, 200);
  gemm_nt<0, 1><<<gGxAb, 256, 0, stream>>>(x0ab, wih0b, bih0b, gxbab, 1536, 600, 200);
  gemm_nt<0, 1><<<gGxTi, 256, 0, stream>>>(x0ti, wih0f, bih0f, gxfti, 256, 600, 200);
  gemm_nt<0, 1><<<gGxTi, 256, 0, stream>>>(x0ti, wih0b, bih0b, gxbti, 256, 600, 200);

  RecurArgs r0;
  r0.gx[0] = gxfab; r0.gx[1] = gxbab; r0.gx[2] = gxfti; r0.gx[3] = gxbti;
  r0.wT[0] = whhT; r0.wT[1] = whhT + 120000; r0.wT[2] = whhT; r0.wT[3] = whhT + 120000;
  r0.bh[0] = bhh0f; r0.bh[1] = bhh0b; r0.bh[2] = bhh0f; r0.bh[3] = bhh0b;
  r0.out[0] = out0ab; r0.out[1] = out0ab; r0.out[2] = out0ti; r0.out[3] = out0ti;
  r0.len[0] = len_ab; r0.len[1] = len_ab; r0.len[2] = len_ti; r0.len[3] = len_ti;
  r0.Tl[0] = 384; r0.Tl[1] = 384; r0.Tl[2] = 64; r0.Tl[3] = 64;
  r0.dir[0] = 0; r0.dir[1] = 1; r0.dir[2] = 0; r0.dir[3] = 1;
  gru_recur<<<4, 640, 0, stream>>>(r0);

  gemm_nt<0, 1><<<gGxAb, 256, 0, stream>>>(out0ab, wih1f, bih1f, gxfab, 1536, 600, 400);
  gemm_nt<0, 1><<<gGxAb, 256, 0, stream>>>(out0ab, wih1b, bih1b, gxbab, 1536, 600, 400);
  gemm_nt<0, 1><<<gGxTi, 256, 0, stream>>>(out0ti, wih1f, bih1f, gxfti, 256, 600, 400);
  gemm_nt<0, 1><<<gGxTi, 256, 0, stream>>>(out0ti, wih1b, bih1b, gxbti, 256, 600, 400);

  RecurArgs r1 = r0;
  r1.wT[0] = whhT + 240000; r1.wT[1] = whhT + 360000;
  r1.wT[2] = whhT + 240000; r1.wT[3] = whhT + 360000;
  r1.bh[0] = bhh1f; r1.bh[1] = bhh1b; r1.bh[2] = bhh1f; r1.bh[3] = bhh1b;
  r1.out[0] = out1ab; r1.out[1] = out1ab; r1.out[2] = out1ti; r1.out[3] = out1ti;
  gru_recur<<<4, 640, 0, stream>>>(r1);

  // ---- xf1 = out1 @ fc1_w^T (no bias; bias folded into attention epilogue) ----
  gemm_nt<0, 0><<<dim3(4, 24), 256, 0, stream>>>(out1ab, fc1w, nullptr, xf1ab, 1536, 200, 400);
  gemm_nt<0, 0><<<dim3(4, 4), 256, 0, stream>>>(out1ti, fc1w, nullptr, xf1ti, 256, 200, 400);

  // ---- fused attention + fc1 + fc2 ----
  attention_fused<<<dim3(875, 4), 512, 0, stream>>>(
      out1ti, xf1ti, out1ab, xf1ab, lab, gnf, fc1b, fc2w, fc2b, (float*)d_out);
}